// Round 7
// baseline (213.581 us; speedup 1.0000x reference)
//
#include <hip/hip_runtime.h>
#include <cstdint>
#include <cstddef>

typedef float f32x16 __attribute__((ext_vector_type(16)));
typedef int i32x4 __attribute__((ext_vector_type(4)));
typedef int i32x8 __attribute__((ext_vector_type(8)));

#define FP8_MAX 448.0f

// async global->LDS, 16B per lane; LDS dest is wave-uniform base + lane*16
#define GL(gp, lp)                                               \
  __builtin_amdgcn_global_load_lds(                              \
      (const __attribute__((address_space(1))) void*)(gp),       \
      (__attribute__((address_space(3))) void*)(lp), 16, 0, 0)

__device__ __forceinline__ uint32_t pack4_e4m3(float a, float b, float c, float d) {
  int p = __builtin_amdgcn_cvt_pk_fp8_f32(a, b, 0, false);
  p = __builtin_amdgcn_cvt_pk_fp8_f32(c, d, p, true);
  return (uint32_t)p;
}

// Fused rowwise quant. Blocks [0,M): input rows -> row-major QA.
// Blocks [M,M+N): weight rows -> K-tile-panel-major QWT:
//   byte k of row n  ->  QWT[(k>>6)*N*64 + n*64 + (k&63)]
// so a 32x32x64-MFMA B-fragment is 2 KiB contiguous.
__global__ __launch_bounds__(256) void quant_rowwise(
    const float* __restrict__ X, const float* __restrict__ W,
    uint8_t* __restrict__ QA, uint8_t* __restrict__ QWT,
    float* __restrict__ xsc, float* __restrict__ wsc, int K, int M, int N) {
  const int row = blockIdx.x;
  const bool is_w = row >= M;
  const int r = is_w ? row - M : row;
  const float* src = (is_w ? W : X) + (size_t)r * K;
  float* rec = (is_w ? wsc : xsc) + r;

  const int tid = threadIdx.x;
  const float4* __restrict__ x4 = (const float4*)src;
  float4 v[4];
  float am = 0.0f;
#pragma unroll
  for (int i = 0; i < 4; ++i) {
    v[i] = x4[i * 256 + tid];
    am = fmaxf(am, fmaxf(fmaxf(fabsf(v[i].x), fabsf(v[i].y)),
                         fmaxf(fabsf(v[i].z), fabsf(v[i].w))));
  }
#pragma unroll
  for (int off = 32; off > 0; off >>= 1)
    am = fmaxf(am, __shfl_xor(am, off));
  __shared__ float smax[4];
  const int wave = tid >> 6, lane = tid & 63;
  if (lane == 0) smax[wave] = am;
  __syncthreads();
  am = fmaxf(fmaxf(smax[0], smax[1]), fmaxf(smax[2], smax[3]));
  am = fmaxf(am, 1e-12f);
  const float scale = FP8_MAX / am;  // exact IEEE div (no fast-math)
  if (tid == 0) rec[0] = 1.0f / scale;

#pragma unroll
  for (int i = 0; i < 4; ++i) {
    float a = fminf(fmaxf(v[i].x * scale, -FP8_MAX), FP8_MAX);
    float b = fminf(fmaxf(v[i].y * scale, -FP8_MAX), FP8_MAX);
    float c = fminf(fmaxf(v[i].z * scale, -FP8_MAX), FP8_MAX);
    float d = fminf(fmaxf(v[i].w * scale, -FP8_MAX), FP8_MAX);
    const uint32_t p = pack4_e4m3(a, b, c, d);
    if (!is_w) {
      ((uint32_t*)(QA + (size_t)r * K))[i * 256 + tid] = p;
    } else {
      // k-bytes (i*256+tid)*4 -> tile i*16+(tid>>4), u32 slot tid&15
      ((uint32_t*)QWT)[(size_t)(i * 16 + (tid >> 4)) * (N * 16) +
                       (size_t)r * 16 + (tid & 15)] = p;
    }
  }
}

// ---------------------------------------------------------------------------
// MX-scaled fp8 GEMM at 2x rate (all E8M0 scales = 1.0 == exact fp8 matmul).
// A-ONLY in LDS (triple-buffer 3x16 KiB, distance-2 DMA prefetch, R5's
// proven 1-barrier/iter counted-vmcnt pipeline + chunk swizzle, rule #21).
// B read DIRECT from global (panel-major QWT -> contiguous 2 KiB/frag,
// L1/L2-served) into ping-pong register sets; B(t+1) loads fly under
// MFMA(t). Cuts per-iter LDS traffic 128 KiB -> 80 KiB (< MFMA 1100 cy).
// vmcnt ledger (in-order retirement): per iter issue {A-stage x2, B x4};
// vmcnt(6) at iter t retires B(t) (MFMA operand) and A(t+1) (pre-confirm
// for next barrier). Loop-top s_barrier: A(t) staged globally + A(t-1)
// reads (lgkm'd last iter) done globally -> STAGE overwrite safe.
// 256x256 tile, 8 waves (2M x 4N); per-wave 128x64 = acc[4][2] f32x16.
// A frag: lane l: row=l&31, k-bytes 32*(l>>5)+0..31. C/D 32x32: col=l&31,
// row=(reg&3)+8*(reg>>2)+4*(l>>5) [m74/m101, dtype-independent].
// ---------------------------------------------------------------------------

#define MMS(TM, TN, A, B)                                          \
  acc[TM][TN] = __builtin_amdgcn_mfma_scale_f32_32x32x64_f8f6f4(   \
      (A), (B), acc[TM][TN], 0, 0, 0, 0x7F7F7F7F, 0, 0x7F7F7F7F);

// stage A K-tile kt (256 rows x 64 B) into abuf bi; wave w covers rows
// [w*32, w*32+32) via two GL16 (16 rows each).
#define STAGEA(KT, BI)                                                     \
  do {                                                                     \
    GL(Aq + aoff + (size_t)(KT) * 64, &lds[(BI) * 16384 + w * 2048]);      \
    GL(Aq + aoff2 + (size_t)(KT) * 64,                                     \
       &lds[(BI) * 16384 + w * 2048 + 1024]);                              \
  } while (0)

// direct B frags (tn=0,1) for K-tile TT into i32x8 B0,B1
#define LOADB(B0, B1, TT)                                                  \
  do {                                                                     \
    const uint8_t* bp = BqT + (size_t)(TT) * nstride + bbase;              \
    i32x4 l0 = *(const i32x4*)(bp);                                        \
    i32x4 h0 = *(const i32x4*)(bp + 16);                                   \
    i32x4 l1 = *(const i32x4*)(bp + 2048);                                 \
    i32x4 h1 = *(const i32x4*)(bp + 2064);                                 \
    B0 = __builtin_shufflevector(l0, h0, 0, 1, 2, 3, 4, 5, 6, 7);          \
    B1 = __builtin_shufflevector(l1, h1, 0, 1, 2, 3, 4, 5, 6, 7);          \
  } while (0)

__device__ __forceinline__ i32x8 ldfrag(const uint8_t* p, int off) {
  i32x4 lo = *(const i32x4*)(p + off);         // logical k-bytes 0-15
  i32x4 hi = *(const i32x4*)(p + (off ^ 16));  // logical k-bytes 16-31
  return __builtin_shufflevector(lo, hi, 0, 1, 2, 3, 4, 5, 6, 7);
}

#define ITER(BC0, BC1, BN0, BN1, T)                                        \
  do {                                                                     \
    __builtin_amdgcn_s_barrier();                                          \
    __builtin_amdgcn_sched_barrier(0);                                     \
    const int pf = ((T) + 2 < nk) ? (T) + 2 : (T);                         \
    const int t1 = ((T) + 1 < nk) ? (T) + 1 : (T);                         \
    STAGEA(pf, ((T) + 2) % 3);                                             \
    LOADB(BN0, BN1, t1);                                                   \
    const int cb = ((T) % 3) * 16384 + arow;                               \
    i32x8 a0 = ldfrag(lds, cb);                                            \
    i32x8 a1 = ldfrag(lds, cb + 2048);                                     \
    i32x8 a2 = ldfrag(lds, cb + 4096);                                     \
    i32x8 a3 = ldfrag(lds, cb + 6144);                                     \
    __builtin_amdgcn_sched_barrier(0);                                     \
    asm volatile("s_waitcnt vmcnt(6) lgkmcnt(0)" ::: "memory");            \
    __builtin_amdgcn_sched_barrier(0);                                     \
    __builtin_amdgcn_s_setprio(1);                                         \
    MMS(0, 0, a0, BC0) MMS(0, 1, a0, BC1)                                  \
    MMS(1, 0, a1, BC0) MMS(1, 1, a1, BC1)                                  \
    MMS(2, 0, a2, BC0) MMS(2, 1, a2, BC1)                                  \
    MMS(3, 0, a3, BC0) MMS(3, 1, a3, BC1)                                  \
    __builtin_amdgcn_s_setprio(0);                                         \
  } while (0)

__global__ __launch_bounds__(512, 1) void gemm_fp8(
    const uint8_t* __restrict__ Aq, const uint8_t* __restrict__ BqT,
    const float* __restrict__ xs, const float* __restrict__ wsc,
    const float* __restrict__ bias, float* __restrict__ C,
    int M, int N, int K) {
  __shared__ __align__(16) uint8_t lds[49152];  // 3 x 16 KiB A buffers
  const int tid = threadIdx.x;
  const int w = tid >> 6, lane = tid & 63;
  const int wrow = w >> 2, wcol = w & 3;

  // XCD-aware bijective swizzle: 512 WGs, 8 XCDs, 64 per XCD.
  int bid = (int)blockIdx.x;
  bid = (bid & 7) * 64 + (bid >> 3);
  const int bm = bid & 31, bn = bid >> 5;
  const int row0 = bm * 256, col0 = bn * 256;

  const int ln31 = lane & 31;
  const size_t nstride = (size_t)N * 64;

  // A staging source (pre-swizzled logical chunk; stored[r][c]=log[r][c^((r>>1)&3)])
  const int srow = lane >> 2;
  const int scol = 16 * ((lane & 3) ^ ((lane >> 3) & 3));
  const size_t aoff = (size_t)(row0 + w * 32 + srow) * K + scol;
  const size_t aoff2 = aoff + (size_t)16 * K;

  // A ds_read base: row = wrow*128 + ln31 (+tm*32), chunk = logical^((r>>1)&3)
  const int g2 = (lane >> 5) * 2;
  const int o0 = 16 * (g2 ^ ((ln31 >> 1) & 3));
  const int arow = (wrow * 128 + ln31) * 64 + o0;

  // B direct-load base (panel-major): col = col0+wcol*64+ln31, k-chunk l>>5
  const size_t bbase = (size_t)(col0 + wcol * 64 + ln31) * 64 + (lane >> 5) * 32;

  f32x16 zero = {};
  f32x16 acc[4][2];
#pragma unroll
  for (int m = 0; m < 4; ++m)
#pragma unroll
    for (int n = 0; n < 2; ++n) acc[m][n] = zero;

  const int nk = K / 64;
  i32x8 bc0, bc1, bn0, bn1;

  // prologue: A(0)->abuf0, A(1)->abuf1, B(0)->bc; confirm own A(0) (vmcnt 6)
  STAGEA(0, 0);
  STAGEA(1, 1);
  LOADB(bc0, bc1, 0);
  __builtin_amdgcn_sched_barrier(0);
  asm volatile("s_waitcnt vmcnt(6)" ::: "memory");

  for (int t = 0; t < nk; t += 2) {
    ITER(bc0, bc1, bn0, bn1, t);
    ITER(bn0, bn1, bc0, bc1, t + 1);
  }

  // epilogue: C/D 32x32 layout col=lane&31, row=(reg&3)+8*(reg>>2)+4*(lane>>5)
  const int cl = lane & 31;
  const int rtop = (lane >> 5) * 4;
#pragma unroll
  for (int tm = 0; tm < 4; ++tm) {
#pragma unroll
    for (int tn = 0; tn < 2; ++tn) {
      const int col = col0 + wcol * 64 + tn * 32 + cl;
      const float wsn = wsc[col];
      const float bb = bias[col];
      const int rowb = row0 + wrow * 128 + tm * 32 + rtop;
#pragma unroll
      for (int q = 0; q < 4; ++q) {
        const float4 xq = *(const float4*)&xs[rowb + 8 * q];
        const float xa[4] = {xq.x, xq.y, xq.z, xq.w};
#pragma unroll
        for (int j = 0; j < 4; ++j) {
          const int r = rowb + 8 * q + j;
          C[(size_t)r * N + col] = fmaf(acc[tm][tn][4 * q + j] * xa[j], wsn, bb);
        }
      }
    }
  }
}

extern "C" void kernel_launch(void* const* d_in, const int* in_sizes, int n_in,
                              void* d_out, int out_size, void* d_ws, size_t ws_size,
                              hipStream_t stream) {
  const float* input = (const float*)d_in[0];   // [M,K] fp32
  const float* weight = (const float*)d_in[1];  // [N,K] fp32
  const float* bias = (const float*)d_in[2];    // [N]   fp32
  float* out = (float*)d_out;                   // [M,N] fp32

  const int K = 4096;
  const int N = in_sizes[2];
  const int M = in_sizes[0] / K;

  uint8_t* qA = (uint8_t*)d_ws;                    // [M,K] row-major
  uint8_t* qWT = qA + (size_t)M * K;               // [K/64][N][64] panel-major
  float* xsc = (float*)(qWT + (size_t)N * K);
  float* wsc = xsc + M;

  quant_rowwise<<<M + N, 256, 0, stream>>>(input, weight, qA, qWT, xsc, wsc,
                                           K, M, N);

  dim3 grid((M / 256) * (N / 256));
  gemm_fp8<<<grid, 512, 0, stream>>>(qA, qWT, xsc, wsc, bias, out, M, N, K);
}